// Round 8
// baseline (161.697 us; speedup 1.0000x reference)
//
#include <hip/hip_runtime.h>
#include <hip/hip_bf16.h>

// B=4, S=2048, E=512, H=8, D=64. out = attn(x@wq+bq, x@wk+bk, x@wv+bv),
// scores MULTIPLIED by 8 (reference divides by D^-0.5).
// Precision: split-bf16 (hi+lo) for Q/K projections and QK^T; bf16 V/PV.
// Round 7: attn bound = vector-load path throughput proportional to total
// load instructions (r5: 1.57GB/194us, r6: 3.1GB/363us, both ~8.4TB/s).
// Fix: 4-wave blocks share K/V via double-buffered LDS staged with
// global_load_lds w=16 (async), both-sides XOR swizzle, 2-phase pipeline.
// Per-wave global loads drop 24 -> 6 per k-tile; reads become ds_read_b128.

#define SE 2048
#define EB 512
#define BB 4
#define HH 8
#define DD 64
#define BHN (BB*HH)

typedef __attribute__((ext_vector_type(8))) short short8;
typedef __attribute__((ext_vector_type(4))) float f32x4;

#define MFMA16(a, b, c) __builtin_amdgcn_mfma_f32_16x16x32_bf16((a), (b), (c), 0, 0, 0)

#if __has_builtin(__builtin_amdgcn_exp2f)
#define EXP2(x) __builtin_amdgcn_exp2f(x)
#else
#define EXP2(x) exp2f(x)
#endif

__device__ __forceinline__ unsigned short f2bf(float f) {
    union { float f; unsigned u; } x; x.f = f;
    unsigned r = x.u + 0x7fffu + ((x.u >> 16) & 1u);
    return (unsigned short)(r >> 16);
}
__device__ __forceinline__ float bf2f(unsigned short b) {
    union { unsigned u; float f; } x; x.u = ((unsigned)b) << 16;
    return x.f;
}

// ---- prep 1: split x (fp32) into hi/lo bf16, vectorized ----
__global__ void xsplit_kernel(const float* __restrict__ x,
                              unsigned short* __restrict__ xh,
                              unsigned short* __restrict__ xl, int n4) {
    int i = blockIdx.x * blockDim.x + threadIdx.x;
    if (i >= n4) return;
    float4 v = reinterpret_cast<const float4*>(x)[i];
    float f[4] = {v.x, v.y, v.z, v.w};
    ushort4 hv, lv;
    unsigned short hh[4], ll[4];
#pragma unroll
    for (int j = 0; j < 4; j++) {
        hh[j] = f2bf(f[j]);
        ll[j] = f2bf(f[j] - bf2f(hh[j]));
    }
    hv.x = hh[0]; hv.y = hh[1]; hv.z = hh[2]; hv.w = hh[3];
    lv.x = ll[0]; lv.y = ll[1]; lv.z = ll[2]; lv.w = ll[3];
    reinterpret_cast<ushort4*>(xh)[i] = hv;
    reinterpret_cast<ushort4*>(xl)[i] = lv;
}

// ---- prep 2: split + transpose weights into wt[hi/lo] layout [3*512 n][512 k] ----
__global__ void wsplit_kernel(const float* __restrict__ wq, const float* __restrict__ wk,
                              const float* __restrict__ wv,
                              unsigned short* __restrict__ wth,
                              unsigned short* __restrict__ wtl) {
    int tid = blockIdx.x * blockDim.x + threadIdx.x;
    if (tid >= 3 * 512 * 512) return;
    int n = tid & 511;
    int k = (tid >> 9) & 511;
    int m = tid >> 18;
    const float* w = (m == 0) ? wq : ((m == 1) ? wk : wv);
    float v = w[k * 512 + n];            // w is [k_in][n_out]
    unsigned short hb = f2bf(v);
    int o = ((m * 512 + n) << 9) + k;    // wt is [n][k]
    wth[o] = hb;
    wtl[o] = f2bf(v - bf2f(hb));
}

// stage 32 rows (4 KB) of a [128][64]-bf16 tile: linear LDS dest,
// inverse-swizzled global source.
__device__ __forceinline__ void stage4(const unsigned short* __restrict__ g,
                                       char* lbase, int wave, int srow, int scol,
                                       int kk) {
#pragma unroll
    for (int j = 0; j < 4; j++) {
        __builtin_amdgcn_global_load_lds(
            (const __attribute__((address_space(1))) void*)(g + (size_t)(srow + j * 8) * 512 + kk + scol),
            (__attribute__((address_space(3))) void*)(lbase + wave * 4096 + j * 1024),
            16, 0, 0);
    }
}

// ---- proj v3: tiled GEMM [8192,512]@[512,512] x3, LDS-staged, swizzled ----
template <int THREE>
__global__ __launch_bounds__(256) void proj_kernel(
    const unsigned short* __restrict__ xh, const unsigned short* __restrict__ xl,
    const unsigned short* __restrict__ wth, const unsigned short* __restrict__ wtl,
    const float* __restrict__ bq, const float* __restrict__ bk, const float* __restrict__ bv,
    unsigned short* __restrict__ qh, unsigned short* __restrict__ ql,
    unsigned short* __restrict__ kh, unsigned short* __restrict__ kl,
    unsigned short* __restrict__ vt) {
    constexpr int NTILE = THREE ? 4 : 2;
    __shared__ unsigned short lds[NTILE * 8192];   // tiles of [128][64] bf16
    char* LB = (char*)lds;
    constexpr int AHB = 0;
    constexpr int ALB = THREE ? 16384 : 0;
    constexpr int BHB = THREE ? 32768 : 16384;
    constexpr int BLB = THREE ? 49152 : 0;

    const int lane = threadIdx.x & 63;
    const int wave = threadIdx.x >> 6;
    const int lr = lane & 15, lk = lane >> 4;
    const int mat = THREE ? blockIdx.z : 2;        // 0=q 1=k 2=v
    const int m0 = blockIdx.x * 128;
    const int n0 = blockIdx.y * 128;
    const int wr = wave >> 1, wc = wave & 1;

    const unsigned short* Ah = xh + (size_t)m0 * 512;
    const unsigned short* Al = xl + (size_t)m0 * 512;
    const unsigned short* Bh = wth + (size_t)(mat * 512 + n0) * 512;
    const unsigned short* Bl = wtl + (size_t)(mat * 512 + n0) * 512;

    const int srow = wave * 32 + (lane >> 3);
    const int scol = 8 * ((lane & 7) ^ (lane >> 3));
    const int swzr = (lr & 7) << 4;

    f32x4 acc[4][4];
#pragma unroll
    for (int mi = 0; mi < 4; mi++)
#pragma unroll
        for (int ni = 0; ni < 4; ni++)
#pragma unroll
            for (int r = 0; r < 4; r++) acc[mi][ni][r] = 0.f;

    for (int t = 0; t < 8; t++) {
        const int kk = t * 64;
        stage4(Ah, LB + AHB, wave, srow, scol, kk);
        if (THREE) stage4(Al, LB + ALB, wave, srow, scol, kk);
        stage4(Bh, LB + BHB, wave, srow, scol, kk);
        if (THREE) stage4(Bl, LB + BLB, wave, srow, scol, kk);
        __syncthreads();

#pragma unroll
        for (int ks = 0; ks < 2; ks++) {
            short8 ah[4], al[4], bh8[4], bl8[4];
            const int cb = (ks * 64 + lk * 16) ^ swzr;
#pragma unroll
            for (int i = 0; i < 4; i++) {
                const int ao = (wr * 64 + i * 16 + lr) * 128 + cb;
                const int bo = (wc * 64 + i * 16 + lr) * 128 + cb;
                ah[i] = *reinterpret_cast<const short8*>(LB + AHB + ao);
                if (THREE) al[i] = *reinterpret_cast<const short8*>(LB + ALB + ao);
                bh8[i] = *reinterpret_cast<const short8*>(LB + BHB + bo);
                if (THREE) bl8[i] = *reinterpret_cast<const short8*>(LB + BLB + bo);
            }
#pragma unroll
            for (int mi = 0; mi < 4; mi++)
#pragma unroll
                for (int ni = 0; ni < 4; ni++) {
                    acc[mi][ni] = MFMA16(ah[mi], bh8[ni], acc[mi][ni]);
                    if (THREE) {
                        acc[mi][ni] = MFMA16(ah[mi], bl8[ni], acc[mi][ni]);
                        acc[mi][ni] = MFMA16(al[mi], bh8[ni], acc[mi][ni]);
                    }
                }
        }
        __syncthreads();
    }

    const float* bias = THREE ? ((mat == 0) ? bq : bk) : bv;
#pragma unroll
    for (int ni = 0; ni < 4; ni++) {
        const int col = n0 + wc * 64 + ni * 16 + lr;
        const float bsv = bias[col];
        const int h = col >> 6, d = col & 63;
#pragma unroll
        for (int mi = 0; mi < 4; mi++) {
#pragma unroll
            for (int r = 0; r < 4; r++) {
                const int row = m0 + wr * 64 + mi * 16 + lk * 4 + r;
                const int b_ = row >> 11, s = row & 2047;
                const int bh_ = b_ * HH + h;
                const float val = acc[mi][ni][r] + bsv;
                if (THREE) {
                    const unsigned short hb = f2bf(val);
                    const int o = (bh_ * SE + s) * DD + d;
                    if (mat == 0) { qh[o] = hb; ql[o] = f2bf(val - bf2f(hb)); }
                    else          { kh[o] = hb; kl[o] = f2bf(val - bf2f(hb)); }
                } else {
                    vt[(bh_ * DD + d) * SE + s] = f2bf(val);
                }
            }
        }
    }
}

// ---- attention v6: 4-wave blocks, K/V shared via double-buffered LDS ----
// Each wave owns 32 q-rows (2x16). Block covers 128 q-rows. KBLK = 64.
// K/V tile (Kh 8KB + Kl 8KB + V^T 8KB) staged once per block per tile via
// global_load_lds (6 instrs/wave), both-sides XOR swizzle; 2-phase pipeline.
// LDS: 2 x 24KB buffers + 4 waves x 4KB P tiles = 64KB.
__global__ __launch_bounds__(256) void attn_kernel(
    const unsigned short* __restrict__ qh, const unsigned short* __restrict__ ql,
    const unsigned short* __restrict__ kh, const unsigned short* __restrict__ kl,
    const unsigned short* __restrict__ vt, float* __restrict__ out) {
    __shared__ char LB[65536];
    const int lane = threadIdx.x & 63, wave = threadIdx.x >> 6;
    const int lr = lane & 15, lk = lane >> 4;
    const int bh = blockIdx.x;               // 0..31
    const int b_ = bh >> 3, h = bh & 7;
    const int q0 = blockIdx.y * 128 + wave * 32;
    const int base = bh * SE * DD;
    const unsigned short* vbase = vt + bh * DD * SE;
    const float CL = 11.54156031f;           // 8 * log2(e)
    const int swz = (lr & 7) << 4;

    // ---- per-wave staging descriptors: chunks c = wave*6 + i (24 x 1KB) ----
    // chunk c: mat = c>>3 (0=Kh,1=Kl,2=V^T), grp = c&7 (rows grp*8..grp*8+7).
    // lane reads 16B at (row = grp*8 + lane>>3, col16 = (lane&7) ^ (lane>>3)).
    const unsigned short* gp[6];
    int ginc[6], goff[6];
    {
        const int rIn = lane >> 3;                 // row within 8-row group
        const int c16 = (lane & 7) ^ rIn;          // inverse-swizzled col
#pragma unroll
        for (int i = 0; i < 6; i++) {
            const int c = wave * 6 + i;
            const int mat = c >> 3, grp = c & 7;
            const int row = grp * 8 + rIn;
            if (mat == 0)      { gp[i] = kh + base + row * DD + c16 * 8;  ginc[i] = 64 * DD; }
            else if (mat == 1) { gp[i] = kl + base + row * DD + c16 * 8;  ginc[i] = 64 * DD; }
            else               { gp[i] = vbase + row * SE + c16 * 8;      ginc[i] = 64; }
            goff[i] = mat * 8192 + grp * 1024;
        }
    }

    // Q fragments (B-operand)
    short8 qhf[2][2], qlf[2][2];
#pragma unroll
    for (int qs = 0; qs < 2; qs++) {
        const int qoff = base + (q0 + qs * 16 + lr) * DD + lk * 8;
        qhf[qs][0] = *reinterpret_cast<const short8*>(qh + qoff);
        qhf[qs][1] = *reinterpret_cast<const short8*>(qh + qoff + 32);
        qlf[qs][0] = *reinterpret_cast<const short8*>(ql + qoff);
        qlf[qs][1] = *reinterpret_cast<const short8*>(ql + qoff + 32);
    }

    float m[2] = {-3.0e4f, -3.0e4f}, l[2] = {0.f, 0.f};
    f32x4 o[2][4];
#pragma unroll
    for (int qs = 0; qs < 2; qs++)
#pragma unroll
        for (int dnt = 0; dnt < 4; dnt++)
#pragma unroll
            for (int r = 0; r < 4; r++) o[qs][dnt][r] = 0.f;

    char* myp = LB + 49152 + wave * 4096;     // per-wave P tiles (2 x 2KB)

    // prologue: stage tile 0 into buffer 0
#pragma unroll
    for (int i = 0; i < 6; i++) {
        __builtin_amdgcn_global_load_lds(
            (const __attribute__((address_space(1))) void*)gp[i],
            (__attribute__((address_space(3))) void*)(LB + goff[i]), 16, 0, 0);
        gp[i] += ginc[i];
    }
    __syncthreads();   // implicit vmcnt(0): tile 0 staged

    for (int kt = 0; kt < 32; kt++) {
        const char* KB = LB + (kt & 1) * 24576;
        // issue next-tile stage first (overlaps with compute below)
        if (kt < 31) {
            const int nb = ((kt + 1) & 1) * 24576;
#pragma unroll
            for (int i = 0; i < 6; i++) {
                __builtin_amdgcn_global_load_lds(
                    (const __attribute__((address_space(1))) void*)gp[i],
                    (__attribute__((address_space(3))) void*)(LB + nb + goff[i]), 16, 0, 0);
                gp[i] += ginc[i];
            }
        }

        f32x4 s[2][4];
#pragma unroll
        for (int qs = 0; qs < 2; qs++)
#pragma unroll
            for (int knt = 0; knt < 4; knt++)
#pragma unroll
                for (int r = 0; r < 4; r++) s[qs][knt][r] = 0.f;

        __builtin_amdgcn_s_setprio(1);
#pragma unroll
        for (int knt = 0; knt < 4; knt++) {
            const int rb = (knt * 16 + lr) * 128;
            short8 kh0 = *reinterpret_cast<const short8*>(KB + rb + ((lk * 16) ^ swz));
            short8 kh1 = *reinterpret_cast<const short8*>(KB + rb + ((64 + lk * 16) ^ swz));
            short8 kl0 = *reinterpret_cast<const short8*>(KB + 8192 + rb + ((lk * 16) ^ swz));
            short8 kl1 = *reinterpret_cast<const short8*>(KB + 8192 + rb + ((64 + lk * 16) ^ swz));
#pragma unroll
            for (int qs = 0; qs < 2; qs++) {
                s[qs][knt] = MFMA16(kh0, qhf[qs][0], s[qs][knt]);
                s[qs][knt] = MFMA16(kh1, qhf[qs][1], s[qs][knt]);
                s[qs][knt] = MFMA16(kl0, qhf[qs][0], s[qs][knt]);
                s[qs][knt] = MFMA16(kl1, qhf[qs][1], s[qs][knt]);
                s[qs][knt] = MFMA16(kh0, qlf[qs][0], s[qs][knt]);
                s[qs][knt] = MFMA16(kh1, qlf[qs][1], s[qs][knt]);
            }
        }
        __builtin_amdgcn_s_setprio(0);

        // V fragments from LDS (latency hides under softmax VALU)
        short8 vf[4][2];
#pragma unroll
        for (int dnt = 0; dnt < 4; dnt++) {
            const int rv = (dnt * 16 + lr) * 128;
            vf[dnt][0] = *reinterpret_cast<const short8*>(KB + 16384 + rv + ((lk * 16) ^ swz));
            vf[dnt][1] = *reinterpret_cast<const short8*>(KB + 16384 + rv + ((64 + lk * 16) ^ swz));
        }

        // softmax (exp2 domain), per-lane q-row
#pragma unroll
        for (int qs = 0; qs < 2; qs++) {
            float mt = s[qs][0][0];
#pragma unroll
            for (int knt = 0; knt < 4; knt++)
#pragma unroll
                for (int r = 0; r < 4; r++) mt = fmaxf(mt, s[qs][knt][r]);
            mt = fmaxf(mt, __shfl_xor(mt, 16));
            mt = fmaxf(mt, __shfl_xor(mt, 32));

            if (!__all(mt <= m[qs] + 0.69314718f)) {   // defer-max
                const float mn = fmaxf(m[qs], mt);
                const float fac = EXP2((m[qs] - mn) * CL);
                l[qs] *= fac;
#pragma unroll
                for (int dnt = 0; dnt < 4; dnt++)
#pragma unroll
                    for (int r = 0; r < 4; r++) o[qs][dnt][r] *= fac;
                m[qs] = mn;
            }
            const float nm = -m[qs] * CL;
            float rs = 0.f;
#pragma unroll
            for (int knt = 0; knt < 4; knt++) {
                float p0 = EXP2(fmaf(s[qs][knt][0], CL, nm));
                float p1 = EXP2(fmaf(s[qs][knt][1], CL, nm));
                float p2 = EXP2(fmaf(s[qs][knt][2], CL, nm));
                float p3 = EXP2(fmaf(s[qs][knt][3], CL, nm));
                rs += (p0 + p1) + (p2 + p3);
                unsigned w0 = (unsigned)f2bf(p0) | ((unsigned)f2bf(p1) << 16);
                unsigned w1 = (unsigned)f2bf(p2) | ((unsigned)f2bf(p3) << 16);
                const int cb = (knt * 32 + lk * 8) ^ swz;
                *reinterpret_cast<uint2*>(myp + qs * 2048 + lr * 128 + cb) =
                    make_uint2(w0, w1);
            }
            rs += __shfl_xor(rs, 16);
            rs += __shfl_xor(rs, 32);
            l[qs] += rs;
        }

        // PV: A = V^T frags, B = P frags from LDS (wave-private)
        __builtin_amdgcn_s_setprio(1);
#pragma unroll
        for (int qs = 0; qs < 2; qs++) {
            const char* mp = myp + qs * 2048;
            short8 pa0 = *reinterpret_cast<const short8*>(mp + lr * 128 + ((lk * 16) ^ swz));
            short8 pa1 = *reinterpret_cast<const short8*>(mp + lr * 128 + ((64 + lk * 16) ^ swz));
#pragma unroll
            for (int dnt = 0; dnt < 4; dnt++) {
                o[qs][dnt] = MFMA16(vf[dnt][0], pa0, o[qs][dnt]);
                o[qs][dnt] = MFMA16(vf[dnt][1], pa1, o[qs][dnt]);
            }
        }
        __builtin_amdgcn_s_setprio(0);

        __syncthreads();   // drains vmcnt (next tile staged) + all LDS reads done
    }

    // epilogue: C[d][q] => lane writes 4 consecutive d (float4) for q-row
#pragma unroll
    for (int qs = 0; qs < 2; qs++) {
        const float rl = 1.0f / l[qs];
        float* op = out + (size_t)(b_ * SE + q0 + qs * 16 + lr) * EB + h * DD + lk * 4;
#pragma unroll
        for (int dnt = 0; dnt < 4; dnt++) {
            float4 val;
            val.x = o[qs][dnt][0] * rl;
            val.y = o[qs][dnt][1] * rl;
            val.z = o[qs][dnt][2] * rl;
            val.w = o[qs][dnt][3] * rl;
            *reinterpret_cast<float4*>(op + dnt * 16) = val;
        }
    }
}

extern "C" void kernel_launch(void* const* d_in, const int* in_sizes, int n_in,
                              void* d_out, int out_size, void* d_ws, size_t ws_size,
                              hipStream_t stream) {
    const float* x  = (const float*)d_in[0];
    const float* wq = (const float*)d_in[1];
    const float* bq = (const float*)d_in[2];
    const float* wk = (const float*)d_in[3];
    const float* bk = (const float*)d_in[4];
    const float* wv = (const float*)d_in[5];
    const float* bv = (const float*)d_in[6];
    float* out = (float*)d_out;

    unsigned short* ws = (unsigned short*)d_ws;
    const int NX = 8192 * 512;
    const int NW = 3 * 512 * 512;
    const int NQ = BHN * SE * DD;
    unsigned short* xh  = ws;
    unsigned short* xl  = xh + NX;
    unsigned short* wth = xl + NX;
    unsigned short* wtl = wth + NW;
    unsigned short* qhp = wtl + NW;
    unsigned short* qlp = qhp + NQ;
    unsigned short* khp = qlp + NQ;
    unsigned short* klp = khp + NQ;
    unsigned short* vtp = klp + NQ;

    xsplit_kernel<<<NX / 4 / 256, 256, 0, stream>>>(x, xh, xl, NX / 4);
    wsplit_kernel<<<NW / 256, 256, 0, stream>>>(wq, wk, wv, wth, wtl);
    proj_kernel<1><<<dim3(64, 4, 2), 256, 0, stream>>>(xh, xl, wth, wtl, bq, bk, bv,
                                                       qhp, qlp, khp, klp, vtp);
    proj_kernel<0><<<dim3(64, 4), 256, 0, stream>>>(xh, xl, wth, wtl, bq, bk, bv,
                                                    qhp, qlp, khp, klp, vtp);
    attn_kernel<<<dim3(32, 16), 256, 0, stream>>>(qhp, qlp, khp, klp, vtp, out);
}

// Round 9
// 161.062 us; speedup vs baseline: 1.0039x; 1.0039x over previous
//
#include <hip/hip_runtime.h>
#include <hip/hip_bf16.h>

// B=4, S=2048, E=512, H=8, D=64. out = attn(x@wq+bq, x@wk+bk, x@wv+bv),
// scores MULTIPLIED by 8 (reference divides by D^-0.5).
// Precision: split-bf16 (hi+lo) for Q/K projections and QK^T; bf16 V/PV.
// Round 7: attn bound = vector-load path throughput proportional to total
// load instructions (r5: 1.57GB/194us, r6: 3.1GB/363us, both ~8.4TB/s).
// Fix: 4-wave blocks share K/V via double-buffered LDS staged with
// global_load_lds w=16 (async), both-sides XOR swizzle, 2-phase pipeline.
// Per-wave global loads drop 24 -> 6 per k-tile; reads become ds_read_b128.

#define SE 2048
#define EB 512
#define BB 4
#define HH 8
#define DD 64
#define BHN (BB*HH)

typedef __attribute__((ext_vector_type(8))) short short8;
typedef __attribute__((ext_vector_type(4))) float f32x4;

#define MFMA16(a, b, c) __builtin_amdgcn_mfma_f32_16x16x32_bf16((a), (b), (c), 0, 0, 0)

#if __has_builtin(__builtin_amdgcn_exp2f)
#define EXP2(x) __builtin_amdgcn_exp2f(x)
#else
#define EXP2(x) exp2f(x)
#endif

__device__ __forceinline__ unsigned short f2bf(float f) {
    union { float f; unsigned u; } x; x.f = f;
    unsigned r = x.u + 0x7fffu + ((x.u >> 16) & 1u);
    return (unsigned short)(r >> 16);
}
__device__ __forceinline__ float bf2f(unsigned short b) {
    union { unsigned u; float f; } x; x.u = ((unsigned)b) << 16;
    return x.f;
}

// ---- prep 1: split x (fp32) into hi/lo bf16, vectorized ----
__global__ void xsplit_kernel(const float* __restrict__ x,
                              unsigned short* __restrict__ xh,
                              unsigned short* __restrict__ xl, int n4) {
    int i = blockIdx.x * blockDim.x + threadIdx.x;
    if (i >= n4) return;
    float4 v = reinterpret_cast<const float4*>(x)[i];
    float f[4] = {v.x, v.y, v.z, v.w};
    ushort4 hv, lv;
    unsigned short hh[4], ll[4];
#pragma unroll
    for (int j = 0; j < 4; j++) {
        hh[j] = f2bf(f[j]);
        ll[j] = f2bf(f[j] - bf2f(hh[j]));
    }
    hv.x = hh[0]; hv.y = hh[1]; hv.z = hh[2]; hv.w = hh[3];
    lv.x = ll[0]; lv.y = ll[1]; lv.z = ll[2]; lv.w = ll[3];
    reinterpret_cast<ushort4*>(xh)[i] = hv;
    reinterpret_cast<ushort4*>(xl)[i] = lv;
}

// ---- prep 2: split + transpose weights into wt[hi/lo] layout [3*512 n][512 k] ----
__global__ void wsplit_kernel(const float* __restrict__ wq, const float* __restrict__ wk,
                              const float* __restrict__ wv,
                              unsigned short* __restrict__ wth,
                              unsigned short* __restrict__ wtl) {
    int tid = blockIdx.x * blockDim.x + threadIdx.x;
    if (tid >= 3 * 512 * 512) return;
    int n = tid & 511;
    int k = (tid >> 9) & 511;
    int m = tid >> 18;
    const float* w = (m == 0) ? wq : ((m == 1) ? wk : wv);
    float v = w[k * 512 + n];            // w is [k_in][n_out]
    unsigned short hb = f2bf(v);
    int o = ((m * 512 + n) << 9) + k;    // wt is [n][k]
    wth[o] = hb;
    wtl[o] = f2bf(v - bf2f(hb));
}

// stage 32 rows (4 KB) of a [128][64]-bf16 tile: linear LDS dest,
// inverse-swizzled global source.
__device__ __forceinline__ void stage4(const unsigned short* __restrict__ g,
                                       char* lbase, int wave, int srow, int scol,
                                       int kk) {
#pragma unroll
    for (int j = 0; j < 4; j++) {
        __builtin_amdgcn_global_load_lds(
            (const __attribute__((address_space(1))) void*)(g + (size_t)(srow + j * 8) * 512 + kk + scol),
            (__attribute__((address_space(3))) void*)(lbase + wave * 4096 + j * 1024),
            16, 0, 0);
    }
}

// ---- proj v3: tiled GEMM [8192,512]@[512,512] x3, LDS-staged, swizzled ----
template <int THREE>
__global__ __launch_bounds__(256) void proj_kernel(
    const unsigned short* __restrict__ xh, const unsigned short* __restrict__ xl,
    const unsigned short* __restrict__ wth, const unsigned short* __restrict__ wtl,
    const float* __restrict__ bq, const float* __restrict__ bk, const float* __restrict__ bv,
    unsigned short* __restrict__ qh, unsigned short* __restrict__ ql,
    unsigned short* __restrict__ kh, unsigned short* __restrict__ kl,
    unsigned short* __restrict__ vt) {
    constexpr int NTILE = THREE ? 4 : 2;
    __shared__ unsigned short lds[NTILE * 8192];   // tiles of [128][64] bf16
    char* LB = (char*)lds;
    constexpr int AHB = 0;
    constexpr int ALB = THREE ? 16384 : 0;
    constexpr int BHB = THREE ? 32768 : 16384;
    constexpr int BLB = THREE ? 49152 : 0;

    const int lane = threadIdx.x & 63;
    const int wave = threadIdx.x >> 6;
    const int lr = lane & 15, lk = lane >> 4;
    const int mat = THREE ? blockIdx.z : 2;        // 0=q 1=k 2=v
    const int m0 = blockIdx.x * 128;
    const int n0 = blockIdx.y * 128;
    const int wr = wave >> 1, wc = wave & 1;

    const unsigned short* Ah = xh + (size_t)m0 * 512;
    const unsigned short* Al = xl + (size_t)m0 * 512;
    const unsigned short* Bh = wth + (size_t)(mat * 512 + n0) * 512;
    const unsigned short* Bl = wtl + (size_t)(mat * 512 + n0) * 512;

    const int srow = wave * 32 + (lane >> 3);
    const int scol = 8 * ((lane & 7) ^ (lane >> 3));
    const int swzr = (lr & 7) << 4;

    f32x4 acc[4][4];
#pragma unroll
    for (int mi = 0; mi < 4; mi++)
#pragma unroll
        for (int ni = 0; ni < 4; ni++)
#pragma unroll
            for (int r = 0; r < 4; r++) acc[mi][ni][r] = 0.f;

    for (int t = 0; t < 8; t++) {
        const int kk = t * 64;
        stage4(Ah, LB + AHB, wave, srow, scol, kk);
        if (THREE) stage4(Al, LB + ALB, wave, srow, scol, kk);
        stage4(Bh, LB + BHB, wave, srow, scol, kk);
        if (THREE) stage4(Bl, LB + BLB, wave, srow, scol, kk);
        __syncthreads();

#pragma unroll
        for (int ks = 0; ks < 2; ks++) {
            short8 ah[4], al[4], bh8[4], bl8[4];
            const int cb = (ks * 64 + lk * 16) ^ swzr;
#pragma unroll
            for (int i = 0; i < 4; i++) {
                const int ao = (wr * 64 + i * 16 + lr) * 128 + cb;
                const int bo = (wc * 64 + i * 16 + lr) * 128 + cb;
                ah[i] = *reinterpret_cast<const short8*>(LB + AHB + ao);
                if (THREE) al[i] = *reinterpret_cast<const short8*>(LB + ALB + ao);
                bh8[i] = *reinterpret_cast<const short8*>(LB + BHB + bo);
                if (THREE) bl8[i] = *reinterpret_cast<const short8*>(LB + BLB + bo);
            }
#pragma unroll
            for (int mi = 0; mi < 4; mi++)
#pragma unroll
                for (int ni = 0; ni < 4; ni++) {
                    acc[mi][ni] = MFMA16(ah[mi], bh8[ni], acc[mi][ni]);
                    if (THREE) {
                        acc[mi][ni] = MFMA16(ah[mi], bl8[ni], acc[mi][ni]);
                        acc[mi][ni] = MFMA16(al[mi], bh8[ni], acc[mi][ni]);
                    }
                }
        }
        __syncthreads();
    }

    const float* bias = THREE ? ((mat == 0) ? bq : bk) : bv;
#pragma unroll
    for (int ni = 0; ni < 4; ni++) {
        const int col = n0 + wc * 64 + ni * 16 + lr;
        const float bsv = bias[col];
        const int h = col >> 6, d = col & 63;
#pragma unroll
        for (int mi = 0; mi < 4; mi++) {
#pragma unroll
            for (int r = 0; r < 4; r++) {
                const int row = m0 + wr * 64 + mi * 16 + lk * 4 + r;
                const int b_ = row >> 11, s = row & 2047;
                const int bh_ = b_ * HH + h;
                const float val = acc[mi][ni][r] + bsv;
                if (THREE) {
                    const unsigned short hb = f2bf(val);
                    const int o = (bh_ * SE + s) * DD + d;
                    if (mat == 0) { qh[o] = hb; ql[o] = f2bf(val - bf2f(hb)); }
                    else          { kh[o] = hb; kl[o] = f2bf(val - bf2f(hb)); }
                } else {
                    vt[(bh_ * DD + d) * SE + s] = f2bf(val);
                }
            }
        }
    }
}

// ---- attention v6: 4-wave blocks, K/V shared via double-buffered LDS ----
// Each wave owns 32 q-rows (2x16). Block covers 128 q-rows. KBLK = 64.
// K/V tile (Kh 8KB + Kl 8KB + V^T 8KB) staged once per block per tile via
// global_load_lds (6 instrs/wave), both-sides XOR swizzle; 2-phase pipeline.
// LDS: 2 x 24KB buffers + 4 waves x 4KB P tiles = 64KB.
__global__ __launch_bounds__(256) void attn_kernel(
    const unsigned short* __restrict__ qh, const unsigned short* __restrict__ ql,
    const unsigned short* __restrict__ kh, const unsigned short* __restrict__ kl,
    const unsigned short* __restrict__ vt, float* __restrict__ out) {
    __shared__ char LB[65536];
    const int lane = threadIdx.x & 63, wave = threadIdx.x >> 6;
    const int lr = lane & 15, lk = lane >> 4;
    const int bh = blockIdx.x;               // 0..31
    const int b_ = bh >> 3, h = bh & 7;
    const int q0 = blockIdx.y * 128 + wave * 32;
    const int base = bh * SE * DD;
    const unsigned short* vbase = vt + bh * DD * SE;
    const float CL = 11.54156031f;           // 8 * log2(e)
    const int swz = (lr & 7) << 4;

    // ---- per-wave staging descriptors: chunks c = wave*6 + i (24 x 1KB) ----
    // chunk c: mat = c>>3 (0=Kh,1=Kl,2=V^T), grp = c&7 (rows grp*8..grp*8+7).
    // lane reads 16B at (row = grp*8 + lane>>3, col16 = (lane&7) ^ (lane>>3)).
    const unsigned short* gp[6];
    int ginc[6], goff[6];
    {
        const int rIn = lane >> 3;                 // row within 8-row group
        const int c16 = (lane & 7) ^ rIn;          // inverse-swizzled col
#pragma unroll
        for (int i = 0; i < 6; i++) {
            const int c = wave * 6 + i;
            const int mat = c >> 3, grp = c & 7;
            const int row = grp * 8 + rIn;
            if (mat == 0)      { gp[i] = kh + base + row * DD + c16 * 8;  ginc[i] = 64 * DD; }
            else if (mat == 1) { gp[i] = kl + base + row * DD + c16 * 8;  ginc[i] = 64 * DD; }
            else               { gp[i] = vbase + row * SE + c16 * 8;      ginc[i] = 64; }
            goff[i] = mat * 8192 + grp * 1024;
        }
    }

    // Q fragments (B-operand)
    short8 qhf[2][2], qlf[2][2];
#pragma unroll
    for (int qs = 0; qs < 2; qs++) {
        const int qoff = base + (q0 + qs * 16 + lr) * DD + lk * 8;
        qhf[qs][0] = *reinterpret_cast<const short8*>(qh + qoff);
        qhf[qs][1] = *reinterpret_cast<const short8*>(qh + qoff + 32);
        qlf[qs][0] = *reinterpret_cast<const short8*>(ql + qoff);
        qlf[qs][1] = *reinterpret_cast<const short8*>(ql + qoff + 32);
    }

    float m[2] = {-3.0e4f, -3.0e4f}, l[2] = {0.f, 0.f};
    f32x4 o[2][4];
#pragma unroll
    for (int qs = 0; qs < 2; qs++)
#pragma unroll
        for (int dnt = 0; dnt < 4; dnt++)
#pragma unroll
            for (int r = 0; r < 4; r++) o[qs][dnt][r] = 0.f;

    char* myp = LB + 49152 + wave * 4096;     // per-wave P tiles (2 x 2KB)

    // prologue: stage tile 0 into buffer 0
#pragma unroll
    for (int i = 0; i < 6; i++) {
        __builtin_amdgcn_global_load_lds(
            (const __attribute__((address_space(1))) void*)gp[i],
            (__attribute__((address_space(3))) void*)(LB + goff[i]), 16, 0, 0);
        gp[i] += ginc[i];
    }
    __syncthreads();   // implicit vmcnt(0): tile 0 staged

    for (int kt = 0; kt < 32; kt++) {
        const char* KB = LB + (kt & 1) * 24576;
        // issue next-tile stage first (overlaps with compute below)
        if (kt < 31) {
            const int nb = ((kt + 1) & 1) * 24576;
#pragma unroll
            for (int i = 0; i < 6; i++) {
                __builtin_amdgcn_global_load_lds(
                    (const __attribute__((address_space(1))) void*)gp[i],
                    (__attribute__((address_space(3))) void*)(LB + nb + goff[i]), 16, 0, 0);
                gp[i] += ginc[i];
            }
        }

        f32x4 s[2][4];
#pragma unroll
        for (int qs = 0; qs < 2; qs++)
#pragma unroll
            for (int knt = 0; knt < 4; knt++)
#pragma unroll
                for (int r = 0; r < 4; r++) s[qs][knt][r] = 0.f;

        __builtin_amdgcn_s_setprio(1);
#pragma unroll
        for (int knt = 0; knt < 4; knt++) {
            const int rb = (knt * 16 + lr) * 128;
            short8 kh0 = *reinterpret_cast<const short8*>(KB + rb + ((lk * 16) ^ swz));
            short8 kh1 = *reinterpret_cast<const short8*>(KB + rb + ((64 + lk * 16) ^ swz));
            short8 kl0 = *reinterpret_cast<const short8*>(KB + 8192 + rb + ((lk * 16) ^ swz));
            short8 kl1 = *reinterpret_cast<const short8*>(KB + 8192 + rb + ((64 + lk * 16) ^ swz));
#pragma unroll
            for (int qs = 0; qs < 2; qs++) {
                s[qs][knt] = MFMA16(kh0, qhf[qs][0], s[qs][knt]);
                s[qs][knt] = MFMA16(kh1, qhf[qs][1], s[qs][knt]);
                s[qs][knt] = MFMA16(kl0, qhf[qs][0], s[qs][knt]);
                s[qs][knt] = MFMA16(kl1, qhf[qs][1], s[qs][knt]);
                s[qs][knt] = MFMA16(kh0, qlf[qs][0], s[qs][knt]);
                s[qs][knt] = MFMA16(kh1, qlf[qs][1], s[qs][knt]);
            }
        }
        __builtin_amdgcn_s_setprio(0);

        // V fragments from LDS (latency hides under softmax VALU)
        short8 vf[4][2];
#pragma unroll
        for (int dnt = 0; dnt < 4; dnt++) {
            const int rv = (dnt * 16 + lr) * 128;
            vf[dnt][0] = *reinterpret_cast<const short8*>(KB + 16384 + rv + ((lk * 16) ^ swz));
            vf[dnt][1] = *reinterpret_cast<const short8*>(KB + 16384 + rv + ((64 + lk * 16) ^ swz));
        }

        // softmax (exp2 domain), per-lane q-row
#pragma unroll
        for (int qs = 0; qs < 2; qs++) {
            float mt = s[qs][0][0];
#pragma unroll
            for (int knt = 0; knt < 4; knt++)
#pragma unroll
                for (int r = 0; r < 4; r++) mt = fmaxf(mt, s[qs][knt][r]);
            mt = fmaxf(mt, __shfl_xor(mt, 16));
            mt = fmaxf(mt, __shfl_xor(mt, 32));

            if (!__all(mt <= m[qs] + 0.69314718f)) {   // defer-max
                const float mn = fmaxf(m[qs], mt);
                const float fac = EXP2((m[qs] - mn) * CL);
                l[qs] *= fac;
#pragma unroll
                for (int dnt = 0; dnt < 4; dnt++)
#pragma unroll
                    for (int r = 0; r < 4; r++) o[qs][dnt][r] *= fac;
                m[qs] = mn;
            }
            const float nm = -m[qs] * CL;
            float rs = 0.f;
#pragma unroll
            for (int knt = 0; knt < 4; knt++) {
                float p0 = EXP2(fmaf(s[qs][knt][0], CL, nm));
                float p1 = EXP2(fmaf(s[qs][knt][1], CL, nm));
                float p2 = EXP2(fmaf(s[qs][knt][2], CL, nm));
                float p3 = EXP2(fmaf(s[qs][knt][3], CL, nm));
                rs += (p0 + p1) + (p2 + p3);
                unsigned w0 = (unsigned)f2bf(p0) | ((unsigned)f2bf(p1) << 16);
                unsigned w1 = (unsigned)f2bf(p2) | ((unsigned)f2bf(p3) << 16);
                const int cb = (knt * 32 + lk * 8) ^ swz;
                *reinterpret_cast<uint2*>(myp + qs * 2048 + lr * 128 + cb) =
                    make_uint2(w0, w1);
            }
            rs += __shfl_xor(rs, 16);
            rs += __shfl_xor(rs, 32);
            l[qs] += rs;
        }

        // PV: A = V^T frags, B = P frags from LDS (wave-private)
        __builtin_amdgcn_s_setprio(1);
#pragma unroll
        for (int qs = 0; qs < 2; qs++) {
            const char* mp = myp + qs * 2048;
            short8 pa0 = *reinterpret_cast<const short8*>(mp + lr * 128 + ((lk * 16) ^ swz));
            short8 pa1 = *reinterpret_cast<const short8*>(mp + lr * 128 + ((64 + lk * 16) ^ swz));
#pragma unroll
            for (int dnt = 0; dnt < 4; dnt++) {
                o[qs][dnt] = MFMA16(vf[dnt][0], pa0, o[qs][dnt]);
                o[qs][dnt] = MFMA16(vf[dnt][1], pa1, o[qs][dnt]);
            }
        }
        __builtin_amdgcn_s_setprio(0);

        __syncthreads();   // drains vmcnt (next tile staged) + all LDS reads done
    }

    // epilogue: C[d][q] => lane writes 4 consecutive d (float4) for q-row
#pragma unroll
    for (int qs = 0; qs < 2; qs++) {
        const float rl = 1.0f / l[qs];
        float* op = out + (size_t)(b_ * SE + q0 + qs * 16 + lr) * EB + h * DD + lk * 4;
#pragma unroll
        for (int dnt = 0; dnt < 4; dnt++) {
            float4 val;
            val.x = o[qs][dnt][0] * rl;
            val.y = o[qs][dnt][1] * rl;
            val.z = o[qs][dnt][2] * rl;
            val.w = o[qs][dnt][3] * rl;
            *reinterpret_cast<float4*>(op + dnt * 16) = val;
        }
    }
}

extern "C" void kernel_launch(void* const* d_in, const int* in_sizes, int n_in,
                              void* d_out, int out_size, void* d_ws, size_t ws_size,
                              hipStream_t stream) {
    const float* x  = (const float*)d_in[0];
    const float* wq = (const float*)d_in[1];
    const float* bq = (const float*)d_in[2];
    const float* wk = (const float*)d_in[3];
    const float* bk = (const float*)d_in[4];
    const float* wv = (const float*)d_in[5];
    const float* bv = (const float*)d_in[6];
    float* out = (float*)d_out;

    unsigned short* ws = (unsigned short*)d_ws;
    const int NX = 8192 * 512;
    const int NW = 3 * 512 * 512;
    const int NQ = BHN * SE * DD;
    unsigned short* xh  = ws;
    unsigned short* xl  = xh + NX;
    unsigned short* wth = xl + NX;
    unsigned short* wtl = wth + NW;
    unsigned short* qhp = wtl + NW;
    unsigned short* qlp = qhp + NQ;
    unsigned short* khp = qlp + NQ;
    unsigned short* klp = khp + NQ;
    unsigned short* vtp = klp + NQ;

    xsplit_kernel<<<NX / 4 / 256, 256, 0, stream>>>(x, xh, xl, NX / 4);
    wsplit_kernel<<<NW / 256, 256, 0, stream>>>(wq, wk, wv, wth, wtl);
    proj_kernel<1><<<dim3(64, 4, 2), 256, 0, stream>>>(xh, xl, wth, wtl, bq, bk, bv,
                                                       qhp, qlp, khp, klp, vtp);
    proj_kernel<0><<<dim3(64, 4), 256, 0, stream>>>(xh, xl, wth, wtl, bq, bk, bv,
                                                    qhp, qlp, khp, klp, vtp);
    attn_kernel<<<dim3(32, 16), 256, 0, stream>>>(qhp, qlp, khp, klp, vtp, out);
}

// Round 10
// 144.963 us; speedup vs baseline: 1.1154x; 1.1111x over previous
//
#include <hip/hip_runtime.h>
#include <hip/hip_bf16.h>

// B=4, S=2048, E=512, H=8, D=64. out = attn(x@wq+bq, x@wk+bk, x@wv+bv),
// scores MULTIPLIED by 8 (reference divides by D^-0.5).
// Precision: split-bf16 (hi+lo) for Q/K projections and QK^T; bf16 V/PV.
// Round 10: attn -> 8 waves/block x 16 q-rows/wave (4096 waves total,
// 16 waves/CU = 4/SIMD at 64KB LDS, launch_bounds(512,4) pins VGPR<=128);
// staging amortized to 3 gload_lds/wave/tile; softmax P-pack uses native
// bf16 casts (compiler emits v_cvt_pk_bf16_f32) instead of manual f2bf.

#define SE 2048
#define EB 512
#define BB 4
#define HH 8
#define DD 64
#define BHN (BB*HH)

typedef __attribute__((ext_vector_type(8))) short short8;
typedef __attribute__((ext_vector_type(4))) float f32x4;

#define MFMA16(a, b, c) __builtin_amdgcn_mfma_f32_16x16x32_bf16((a), (b), (c), 0, 0, 0)

#if __has_builtin(__builtin_amdgcn_exp2f)
#define EXP2(x) __builtin_amdgcn_exp2f(x)
#else
#define EXP2(x) exp2f(x)
#endif

__device__ __forceinline__ unsigned short f2bf(float f) {
    union { float f; unsigned u; } x; x.f = f;
    unsigned r = x.u + 0x7fffu + ((x.u >> 16) & 1u);
    return (unsigned short)(r >> 16);
}
__device__ __forceinline__ float bf2f(unsigned short b) {
    union { unsigned u; float f; } x; x.u = ((unsigned)b) << 16;
    return x.f;
}
// native cast pack: compiler lowers pairs to v_cvt_pk_bf16_f32 (RNE)
__device__ __forceinline__ unsigned packbf2(float a, float b) {
    unsigned short lo = __bfloat16_as_ushort(__float2bfloat16(a));
    unsigned short hi = __bfloat16_as_ushort(__float2bfloat16(b));
    return (unsigned)lo | ((unsigned)hi << 16);
}

// ---- prep 1: split x (fp32) into hi/lo bf16, vectorized ----
__global__ void xsplit_kernel(const float* __restrict__ x,
                              unsigned short* __restrict__ xh,
                              unsigned short* __restrict__ xl, int n4) {
    int i = blockIdx.x * blockDim.x + threadIdx.x;
    if (i >= n4) return;
    float4 v = reinterpret_cast<const float4*>(x)[i];
    float f[4] = {v.x, v.y, v.z, v.w};
    ushort4 hv, lv;
    unsigned short hh[4], ll[4];
#pragma unroll
    for (int j = 0; j < 4; j++) {
        hh[j] = f2bf(f[j]);
        ll[j] = f2bf(f[j] - bf2f(hh[j]));
    }
    hv.x = hh[0]; hv.y = hh[1]; hv.z = hh[2]; hv.w = hh[3];
    lv.x = ll[0]; lv.y = ll[1]; lv.z = ll[2]; lv.w = ll[3];
    reinterpret_cast<ushort4*>(xh)[i] = hv;
    reinterpret_cast<ushort4*>(xl)[i] = lv;
}

// ---- prep 2: split + transpose weights into wt[hi/lo] layout [3*512 n][512 k] ----
__global__ void wsplit_kernel(const float* __restrict__ wq, const float* __restrict__ wk,
                              const float* __restrict__ wv,
                              unsigned short* __restrict__ wth,
                              unsigned short* __restrict__ wtl) {
    int tid = blockIdx.x * blockDim.x + threadIdx.x;
    if (tid >= 3 * 512 * 512) return;
    int n = tid & 511;
    int k = (tid >> 9) & 511;
    int m = tid >> 18;
    const float* w = (m == 0) ? wq : ((m == 1) ? wk : wv);
    float v = w[k * 512 + n];            // w is [k_in][n_out]
    unsigned short hb = f2bf(v);
    int o = ((m * 512 + n) << 9) + k;    // wt is [n][k]
    wth[o] = hb;
    wtl[o] = f2bf(v - bf2f(hb));
}

// stage 32 rows (4 KB) of a [128][64]-bf16 tile: linear LDS dest,
// inverse-swizzled global source.
__device__ __forceinline__ void stage4(const unsigned short* __restrict__ g,
                                       char* lbase, int wave, int srow, int scol,
                                       int kk) {
#pragma unroll
    for (int j = 0; j < 4; j++) {
        __builtin_amdgcn_global_load_lds(
            (const __attribute__((address_space(1))) void*)(g + (size_t)(srow + j * 8) * 512 + kk + scol),
            (__attribute__((address_space(3))) void*)(lbase + wave * 4096 + j * 1024),
            16, 0, 0);
    }
}

// ---- proj v3: tiled GEMM [8192,512]@[512,512] x3, LDS-staged, swizzled ----
template <int THREE>
__global__ __launch_bounds__(256) void proj_kernel(
    const unsigned short* __restrict__ xh, const unsigned short* __restrict__ xl,
    const unsigned short* __restrict__ wth, const unsigned short* __restrict__ wtl,
    const float* __restrict__ bq, const float* __restrict__ bk, const float* __restrict__ bv,
    unsigned short* __restrict__ qh, unsigned short* __restrict__ ql,
    unsigned short* __restrict__ kh, unsigned short* __restrict__ kl,
    unsigned short* __restrict__ vt) {
    constexpr int NTILE = THREE ? 4 : 2;
    __shared__ unsigned short lds[NTILE * 8192];   // tiles of [128][64] bf16
    char* LB = (char*)lds;
    constexpr int AHB = 0;
    constexpr int ALB = THREE ? 16384 : 0;
    constexpr int BHB = THREE ? 32768 : 16384;
    constexpr int BLB = THREE ? 49152 : 0;

    const int lane = threadIdx.x & 63;
    const int wave = threadIdx.x >> 6;
    const int lr = lane & 15, lk = lane >> 4;
    const int mat = THREE ? blockIdx.z : 2;        // 0=q 1=k 2=v
    const int m0 = blockIdx.x * 128;
    const int n0 = blockIdx.y * 128;
    const int wr = wave >> 1, wc = wave & 1;

    const unsigned short* Ah = xh + (size_t)m0 * 512;
    const unsigned short* Al = xl + (size_t)m0 * 512;
    const unsigned short* Bh = wth + (size_t)(mat * 512 + n0) * 512;
    const unsigned short* Bl = wtl + (size_t)(mat * 512 + n0) * 512;

    const int srow = wave * 32 + (lane >> 3);
    const int scol = 8 * ((lane & 7) ^ (lane >> 3));
    const int swzr = (lr & 7) << 4;

    f32x4 acc[4][4];
#pragma unroll
    for (int mi = 0; mi < 4; mi++)
#pragma unroll
        for (int ni = 0; ni < 4; ni++)
#pragma unroll
            for (int r = 0; r < 4; r++) acc[mi][ni][r] = 0.f;

    for (int t = 0; t < 8; t++) {
        const int kk = t * 64;
        stage4(Ah, LB + AHB, wave, srow, scol, kk);
        if (THREE) stage4(Al, LB + ALB, wave, srow, scol, kk);
        stage4(Bh, LB + BHB, wave, srow, scol, kk);
        if (THREE) stage4(Bl, LB + BLB, wave, srow, scol, kk);
        __syncthreads();

#pragma unroll
        for (int ks = 0; ks < 2; ks++) {
            short8 ah[4], al[4], bh8[4], bl8[4];
            const int cb = (ks * 64 + lk * 16) ^ swzr;
#pragma unroll
            for (int i = 0; i < 4; i++) {
                const int ao = (wr * 64 + i * 16 + lr) * 128 + cb;
                const int bo = (wc * 64 + i * 16 + lr) * 128 + cb;
                ah[i] = *reinterpret_cast<const short8*>(LB + AHB + ao);
                if (THREE) al[i] = *reinterpret_cast<const short8*>(LB + ALB + ao);
                bh8[i] = *reinterpret_cast<const short8*>(LB + BHB + bo);
                if (THREE) bl8[i] = *reinterpret_cast<const short8*>(LB + BLB + bo);
            }
#pragma unroll
            for (int mi = 0; mi < 4; mi++)
#pragma unroll
                for (int ni = 0; ni < 4; ni++) {
                    acc[mi][ni] = MFMA16(ah[mi], bh8[ni], acc[mi][ni]);
                    if (THREE) {
                        acc[mi][ni] = MFMA16(ah[mi], bl8[ni], acc[mi][ni]);
                        acc[mi][ni] = MFMA16(al[mi], bh8[ni], acc[mi][ni]);
                    }
                }
        }
        __syncthreads();
    }

    const float* bias = THREE ? ((mat == 0) ? bq : bk) : bv;
#pragma unroll
    for (int ni = 0; ni < 4; ni++) {
        const int col = n0 + wc * 64 + ni * 16 + lr;
        const float bsv = bias[col];
        const int h = col >> 6, d = col & 63;
#pragma unroll
        for (int mi = 0; mi < 4; mi++) {
#pragma unroll
            for (int r = 0; r < 4; r++) {
                const int row = m0 + wr * 64 + mi * 16 + lk * 4 + r;
                const int b_ = row >> 11, s = row & 2047;
                const int bh_ = b_ * HH + h;
                const float val = acc[mi][ni][r] + bsv;
                if (THREE) {
                    const unsigned short hb = f2bf(val);
                    const int o = (bh_ * SE + s) * DD + d;
                    if (mat == 0) { qh[o] = hb; ql[o] = f2bf(val - bf2f(hb)); }
                    else          { kh[o] = hb; kl[o] = f2bf(val - bf2f(hb)); }
                } else {
                    vt[(bh_ * DD + d) * SE + s] = f2bf(val);
                }
            }
        }
    }
}

// ---- attention v7: 8-wave blocks, 16 q-rows/wave, K/V shared via LDS dbuf ----
// Block covers 128 q-rows. KBLK = 64. K/V tile (Kh+Kl+V^T = 24KB) staged once
// per block per tile via global_load_lds (3 instrs/wave), XOR-swizzled,
// 2-phase pipeline. LDS: 2x24KB dbuf + 8 waves x 2KB P = 64KB -> 2 blocks/CU
// -> 16 waves/CU = 4/SIMD (round-9 was 2/SIMD; per-wave work halved, totals
// unchanged -> pure latency hiding).
__global__ __launch_bounds__(512, 4) void attn_kernel(
    const unsigned short* __restrict__ qh, const unsigned short* __restrict__ ql,
    const unsigned short* __restrict__ kh, const unsigned short* __restrict__ kl,
    const unsigned short* __restrict__ vt, float* __restrict__ out) {
    __shared__ char LB[65536];
    const int lane = threadIdx.x & 63, wave = threadIdx.x >> 6;
    const int lr = lane & 15, lk = lane >> 4;
    const int bh = blockIdx.x;               // 0..31
    const int b_ = bh >> 3, h = bh & 7;
    const int q0 = blockIdx.y * 128 + wave * 16;
    const int base = bh * SE * DD;
    const unsigned short* vbase = vt + bh * DD * SE;
    const float CL = 11.54156031f;           // 8 * log2(e)
    const int swz = (lr & 7) << 4;

    // ---- staging: 24 chunks of 1KB; wave handles c = wave*3 + i ----
    // chunk c: mat = c>>3 (0=Kh,1=Kl,2=V^T), grp = c&7 (rows grp*8..grp*8+7).
    const unsigned short* gp[3];
    int ginc[3], goff[3];
    {
        const int rIn = lane >> 3;                 // row within 8-row group
        const int c16 = (lane & 7) ^ rIn;          // inverse-swizzled col
#pragma unroll
        for (int i = 0; i < 3; i++) {
            const int c = wave * 3 + i;
            const int mat = c >> 3, grp = c & 7;
            const int row = grp * 8 + rIn;
            if (mat == 0)      { gp[i] = kh + base + row * DD + c16 * 8;  ginc[i] = 64 * DD; }
            else if (mat == 1) { gp[i] = kl + base + row * DD + c16 * 8;  ginc[i] = 64 * DD; }
            else               { gp[i] = vbase + row * SE + c16 * 8;      ginc[i] = 64; }
            goff[i] = mat * 8192 + grp * 1024;
        }
    }

    // Q fragments (B-operand), 16 q-rows
    short8 qhf[2], qlf[2];
    {
        const int qoff = base + (q0 + lr) * DD + lk * 8;
        qhf[0] = *reinterpret_cast<const short8*>(qh + qoff);
        qhf[1] = *reinterpret_cast<const short8*>(qh + qoff + 32);
        qlf[0] = *reinterpret_cast<const short8*>(ql + qoff);
        qlf[1] = *reinterpret_cast<const short8*>(ql + qoff + 32);
    }

    float m = -3.0e4f, l = 0.f;
    f32x4 o[4];
#pragma unroll
    for (int dnt = 0; dnt < 4; dnt++)
#pragma unroll
        for (int r = 0; r < 4; r++) o[dnt][r] = 0.f;

    char* myp = LB + 49152 + wave * 2048;     // per-wave P tile (2KB)

    // prologue: stage tile 0 into buffer 0
#pragma unroll
    for (int i = 0; i < 3; i++) {
        __builtin_amdgcn_global_load_lds(
            (const __attribute__((address_space(1))) void*)gp[i],
            (__attribute__((address_space(3))) void*)(LB + goff[i]), 16, 0, 0);
        gp[i] += ginc[i];
    }
    __syncthreads();   // implicit vmcnt(0): tile 0 staged

    for (int kt = 0; kt < 32; kt++) {
        const char* KB = LB + (kt & 1) * 24576;
        // issue next-tile stage first (overlaps with compute below)
        if (kt < 31) {
            const int nb = ((kt + 1) & 1) * 24576;
#pragma unroll
            for (int i = 0; i < 3; i++) {
                __builtin_amdgcn_global_load_lds(
                    (const __attribute__((address_space(1))) void*)gp[i],
                    (__attribute__((address_space(3))) void*)(LB + nb + goff[i]), 16, 0, 0);
                gp[i] += ginc[i];
            }
        }

        f32x4 s[4];
#pragma unroll
        for (int knt = 0; knt < 4; knt++)
#pragma unroll
            for (int r = 0; r < 4; r++) s[knt][r] = 0.f;

        __builtin_amdgcn_s_setprio(1);
#pragma unroll
        for (int knt = 0; knt < 4; knt++) {
            const int rb = (knt * 16 + lr) * 128;
            short8 kh0 = *reinterpret_cast<const short8*>(KB + rb + ((lk * 16) ^ swz));
            short8 kh1 = *reinterpret_cast<const short8*>(KB + rb + ((64 + lk * 16) ^ swz));
            short8 kl0 = *reinterpret_cast<const short8*>(KB + 8192 + rb + ((lk * 16) ^ swz));
            short8 kl1 = *reinterpret_cast<const short8*>(KB + 8192 + rb + ((64 + lk * 16) ^ swz));
            s[knt] = MFMA16(kh0, qhf[0], s[knt]);
            s[knt] = MFMA16(kh1, qhf[1], s[knt]);
            s[knt] = MFMA16(kl0, qhf[0], s[knt]);
            s[knt] = MFMA16(kl1, qhf[1], s[knt]);
            s[knt] = MFMA16(kh0, qlf[0], s[knt]);
            s[knt] = MFMA16(kh1, qlf[1], s[knt]);
        }
        __builtin_amdgcn_s_setprio(0);

        // V fragments from LDS (latency hides under softmax VALU)
        short8 vf[4][2];
#pragma unroll
        for (int dnt = 0; dnt < 4; dnt++) {
            const int rv = (dnt * 16 + lr) * 128;
            vf[dnt][0] = *reinterpret_cast<const short8*>(KB + 16384 + rv + ((lk * 16) ^ swz));
            vf[dnt][1] = *reinterpret_cast<const short8*>(KB + 16384 + rv + ((64 + lk * 16) ^ swz));
        }

        // softmax (exp2 domain), per-lane q-row
        float mt = s[0][0];
#pragma unroll
        for (int knt = 0; knt < 4; knt++)
#pragma unroll
            for (int r = 0; r < 4; r++) mt = fmaxf(mt, s[knt][r]);
        mt = fmaxf(mt, __shfl_xor(mt, 16));
        mt = fmaxf(mt, __shfl_xor(mt, 32));

        if (!__all(mt <= m + 0.69314718f)) {   // defer-max (P bounded by 2^8)
            const float mn = fmaxf(m, mt);
            const float fac = EXP2((m - mn) * CL);
            l *= fac;
#pragma unroll
            for (int dnt = 0; dnt < 4; dnt++)
#pragma unroll
                for (int r = 0; r < 4; r++) o[dnt][r] *= fac;
            m = mn;
        }
        const float nm = -m * CL;
        float rs = 0.f;
#pragma unroll
        for (int knt = 0; knt < 4; knt++) {
            float p0 = EXP2(fmaf(s[knt][0], CL, nm));
            float p1 = EXP2(fmaf(s[knt][1], CL, nm));
            float p2 = EXP2(fmaf(s[knt][2], CL, nm));
            float p3 = EXP2(fmaf(s[knt][3], CL, nm));
            rs += (p0 + p1) + (p2 + p3);
            // native casts -> compiler emits v_cvt_pk_bf16_f32 (RNE)
            unsigned w0 = packbf2(p0, p1);
            unsigned w1 = packbf2(p2, p3);
            const int cb = (knt * 32 + lk * 8) ^ swz;
            *reinterpret_cast<uint2*>(myp + lr * 128 + cb) = make_uint2(w0, w1);
        }
        rs += __shfl_xor(rs, 16);
        rs += __shfl_xor(rs, 32);
        l += rs;

        // PV: A = V^T frags, B = P frags from LDS (wave-private)
        short8 pa0 = *reinterpret_cast<const short8*>(myp + lr * 128 + ((lk * 16) ^ swz));
        short8 pa1 = *reinterpret_cast<const short8*>(myp + lr * 128 + ((64 + lk * 16) ^ swz));
        __builtin_amdgcn_s_setprio(1);
#pragma unroll
        for (int dnt = 0; dnt < 4; dnt++) {
            o[dnt] = MFMA16(vf[dnt][0], pa0, o[dnt]);
            o[dnt] = MFMA16(vf[dnt][1], pa1, o[dnt]);
        }
        __builtin_amdgcn_s_setprio(0);

        __syncthreads();   // drains vmcnt (next tile staged) + all LDS reads done
    }

    // epilogue: C[d][q] => lane writes 4 consecutive d (float4) for q = q0+lr
    const float rl = 1.0f / l;
    float* op = out + (size_t)(b_ * SE + q0 + lr) * EB + h * DD + lk * 4;
#pragma unroll
    for (int dnt = 0; dnt < 4; dnt++) {
        float4 val;
        val.x = o[dnt][0] * rl;
        val.y = o[dnt][1] * rl;
        val.z = o[dnt][2] * rl;
        val.w = o[dnt][3] * rl;
        *reinterpret_cast<float4*>(op + dnt * 16) = val;
    }
}

extern "C" void kernel_launch(void* const* d_in, const int* in_sizes, int n_in,
                              void* d_out, int out_size, void* d_ws, size_t ws_size,
                              hipStream_t stream) {
    const float* x  = (const float*)d_in[0];
    const float* wq = (const float*)d_in[1];
    const float* bq = (const float*)d_in[2];
    const float* wk = (const float*)d_in[3];
    const float* bk = (const float*)d_in[4];
    const float* wv = (const float*)d_in[5];
    const float* bv = (const float*)d_in[6];
    float* out = (float*)d_out;

    unsigned short* ws = (unsigned short*)d_ws;
    const int NX = 8192 * 512;
    const int NW = 3 * 512 * 512;
    const int NQ = BHN * SE * DD;
    unsigned short* xh  = ws;
    unsigned short* xl  = xh + NX;
    unsigned short* wth = xl + NX;
    unsigned short* wtl = wth + NW;
    unsigned short* qhp = wtl + NW;
    unsigned short* qlp = qhp + NQ;
    unsigned short* khp = qlp + NQ;
    unsigned short* klp = khp + NQ;
    unsigned short* vtp = klp + NQ;

    xsplit_kernel<<<NX / 4 / 256, 256, 0, stream>>>(x, xh, xl, NX / 4);
    wsplit_kernel<<<NW / 256, 256, 0, stream>>>(wq, wk, wv, wth, wtl);
    proj_kernel<1><<<dim3(64, 4, 2), 256, 0, stream>>>(xh, xl, wth, wtl, bq, bk, bv,
                                                       qhp, qlp, khp, klp, vtp);
    proj_kernel<0><<<dim3(64, 4), 256, 0, stream>>>(xh, xl, wth, wtl, bq, bk, bv,
                                                    qhp, qlp, khp, klp, vtp);
    attn_kernel<<<dim3(32, 16), 512, 0, stream>>>(qhp, qlp, khp, klp, vtp, out);
}